// Round 10
// baseline (1286.668 us; speedup 1.0000x reference)
//
#include <hip/hip_runtime.h>

#define NN 250000
#define EE 1000000
#define SS 1000
#define DD 64
#define FIN 16
#define FEE 8
#define NL 3
#define LDH 72  // band row stride (bf16 elems); 144B row -> 2-way bank alias (free)
#define SCHUNK 1024
#define SNB ((NN + SCHUNK - 1) / SCHUNK)  // 245

typedef __attribute__((ext_vector_type(8))) short bf16x8;
typedef __attribute__((ext_vector_type(4))) float f32x4;

static __device__ __forceinline__ short f2bf(float f) {
  union { float f; unsigned u; } v{f};
  unsigned r = (v.u + 0x7fffu + ((v.u >> 16) & 1u)) >> 16;  // RNE
  return (short)r;
}
static __device__ __forceinline__ float bfl(unsigned u) {
  union { unsigned u; float f; } v{u << 16};
  return v.f;
}
static __device__ __forceinline__ float bfh(unsigned u) {
  union { unsigned u; float f; } v{u & 0xffff0000u};
  return v.f;
}
static __device__ __forceinline__ float bfu(unsigned short u) {
  union { unsigned u; float f; } v{(unsigned)u << 16};
  return v.f;
}
static __device__ __forceinline__ unsigned pack2(float a, float b) {
  return (unsigned)(unsigned short)f2bf(a) | ((unsigned)(unsigned short)f2bf(b) << 16);
}
static __device__ __forceinline__ void unp8(uint4 v, float* o) {
  o[0] = bfl(v.x); o[1] = bfh(v.x); o[2] = bfl(v.y); o[3] = bfh(v.y);
  o[4] = bfl(v.z); o[5] = bfh(v.z); o[6] = bfl(v.w); o[7] = bfh(v.w);
}

// ---------------- histogram ----------------
__global__ __launch_bounds__(256) void k_hist(const int* __restrict__ idx,
                                              int* __restrict__ cnt, int n) {
  int i = blockIdx.x * 256 + threadIdx.x;
  if (i < n) atomicAdd(&cnt[idx[i]], 1);
}

// ---------------- block-local exclusive scan (chunk=1024) ----------------
__global__ __launch_bounds__(256) void k_scan1(const int* __restrict__ cntv,
                                               int* __restrict__ off,
                                               int* __restrict__ curs,
                                               int* __restrict__ bsums, int n) {
  __shared__ int ls[256];
  int b = blockIdx.x, t = threadIdx.x;
  int base = b * SCHUNK + t * 4;
  int v[4];
#pragma unroll
  for (int j = 0; j < 4; j++) v[j] = (base + j < n) ? cntv[base + j] : 0;
  int s4 = v[0] + v[1] + v[2] + v[3];
  ls[t] = s4;
  __syncthreads();
  for (int o = 1; o < 256; o <<= 1) {
    int x = (t >= o) ? ls[t - o] : 0;
    __syncthreads();
    ls[t] += x;
    __syncthreads();
  }
  int run = ls[t] - s4;
#pragma unroll
  for (int j = 0; j < 4; j++) {
    if (base + j < n) { off[base + j] = run; curs[base + j] = run; }
    run += v[j];
  }
  if (t == 255) bsums[b] = ls[255];
}

__global__ __launch_bounds__(256) void k_scan2(int* __restrict__ bsums, int nb) {
  __shared__ int ls[256];
  int t = threadIdx.x;
  int v = (t < nb) ? bsums[t] : 0;
  ls[t] = v;
  __syncthreads();
  for (int o = 1; o < 256; o <<= 1) {
    int x = (t >= o) ? ls[t - o] : 0;
    __syncthreads();
    ls[t] += x;
    __syncthreads();
  }
  if (t < nb) bsums[t] = ls[t] - v;  // exclusive
}

__global__ __launch_bounds__(256) void k_scan3(int* __restrict__ off,
                                               int* __restrict__ curs,
                                               const int* __restrict__ bsums, int n) {
  int b = blockIdx.x, t = threadIdx.x;
  int add = bsums[b];
  int base = b * SCHUNK + t * 4;
#pragma unroll
  for (int j = 0; j < 4; j++)
    if (base + j < n) { off[base + j] += add; curs[base + j] += add; }
}

// ---------------- bucket scatter: src + bf16 edge-attrs in CSR order ----------------
__global__ __launch_bounds__(256) void k_bucket_e(const int* __restrict__ src,
                                                  const int* __restrict__ dst,
                                                  const float* __restrict__ ea,
                                                  int* __restrict__ curs,
                                                  int* __restrict__ ssrc,
                                                  unsigned short* __restrict__ eas) {
  int e = blockIdx.x * 256 + threadIdx.x;
  if (e >= EE) return;
  int pos = atomicAdd(&curs[dst[e]], 1);
  ssrc[pos] = src[e];
  const float* a = &ea[(size_t)e * 8];
  uint4 p;
  p.x = pack2(a[0], a[1]);
  p.y = pack2(a[2], a[3]);
  p.z = pack2(a[4], a[5]);
  p.w = pack2(a[6], a[7]);
  *(uint4*)&eas[(size_t)pos * 8] = p;
}

__global__ __launch_bounds__(256) void k_bucket_n(const int* __restrict__ nidx,
                                                  int* __restrict__ curs,
                                                  int* __restrict__ nsorted) {
  int n = blockIdx.x * 256 + threadIdx.x;
  if (n >= NN) return;
  int pos = atomicAdd(&curs[nidx[n]], 1);
  nsorted[pos] = n;
}

__global__ __launch_bounds__(256) void k_cinv(const int* __restrict__ ncnt,
                                              float* __restrict__ cinv) {
  int s = blockIdx.x * 256 + threadIdx.x;
  if (s < SS) {
    float c = (float)ncnt[s];
    cinv[s] = 1.0f / (c < 1.0f ? 1.0f : c);
  }
}

// ---------------- init encoder: hb = bf16(x @ W_init + b) ----------------
__global__ __launch_bounds__(256) void k_init(const float* __restrict__ x,
                                              const float* __restrict__ W,
                                              const float* __restrict__ b,
                                              unsigned short* __restrict__ hb) {
  int gid = blockIdx.x * 256 + threadIdx.x;
  int n = gid >> 6, d = gid & 63;
  const float* xr = x + (size_t)n * FIN;
  float acc = b[d];
#pragma unroll
  for (int k = 0; k < FIN; k++) acc += xr[k] * W[k * DD + d];
  hb[gid] = (unsigned short)f2bf(acc);
}

// ---------------- weight prep: bf16 W^T ----------------
struct WPrep { const float* W[8]; };

__global__ __launch_bounds__(256) void k_wprep(WPrep P, short* __restrict__ wbt) {
  int gid = blockIdx.x * 256 + threadIdx.x;  // 24*4096
  int slot = gid >> 12;
  int e = gid & 4095;
  int n = e >> 6, k = e & 63;
  int bg = slot / NL, l = slot % NL;
  float v = P.W[bg][(size_t)l * 4096 + k * 64 + n];
  wbt[gid] = f2bf(v);
}

// ---------------- segment mean (bf16 out) ----------------
__global__ __launch_bounds__(256) void k_gmean(const unsigned short* __restrict__ hb,
                                               const int* __restrict__ nsorted,
                                               const int* __restrict__ noff,
                                               const int* __restrict__ ncnt,
                                               const float* __restrict__ cinv,
                                               unsigned short* __restrict__ gsumb) {
  __shared__ float red[256];
  int s = blockIdx.x;
  int tid = threadIdx.x;
  int ch = tid & 63, r = tid >> 6;
  int base = noff[s], c = ncnt[s];
  float acc = 0.0f;
  int i = r;
  for (; i + 12 < c; i += 16) {
    int n0 = nsorted[base + i];
    int n1 = nsorted[base + i + 4];
    int n2 = nsorted[base + i + 8];
    int n3 = nsorted[base + i + 12];
    acc += bfu(hb[(size_t)n0 * 64 + ch]) + bfu(hb[(size_t)n1 * 64 + ch]) +
           bfu(hb[(size_t)n2 * 64 + ch]) + bfu(hb[(size_t)n3 * 64 + ch]);
  }
  for (; i < c; i += 4) acc += bfu(hb[(size_t)nsorted[base + i] * 64 + ch]);
  red[tid] = acc;
  __syncthreads();
  if (r == 0) {
    float vsum = red[ch] + red[64 + ch] + red[128 + ch] + red[192 + ch];
    gsumb[s * 64 + ch] = (unsigned short)f2bf(vsum * cinv[s]);
  }
}

// ---------------- fused node kernel: edge-agg + 4x(MLP+LN), wave-autonomous ----------------
struct NodeArgs {
  const unsigned short* hb;
  const unsigned short* gsumb;
  const unsigned short* eas;
  const int* ssrc;
  const int* eoff;
  const int* ecnt;
  const float* We;
  const float* be;
  const int* nidx;
  const int* root;
  const int* tr;
  const float* eps[4];
  const short* wt1[4];
  const short* wt2[4];
  const float* b1[4];
  const float* b2[4];
  const float* ga[4];
  const float* bb[4];
  unsigned short* hbout;
};

// (256,6) + branch loop unroll=1: total reg demand (arch+acc, unified file)
// must fit 512/6=85. R9's fully-unrolled loop demanded ~100 -> spill
// (WRITE_SIZE 136MB). One-branch-at-a-time live ranges fit the budget.
__global__ __launch_bounds__(256, 6) void k_node(NodeArgs A) {
  __shared__ short sT[4][16 * LDH];  // per-wave band (DS ops are wave-in-order: no barriers)
  int tid = threadIdx.x;
  int wv = tid >> 6;
  int lane = tid & 63;
  int m = lane & 15, q = lane >> 4;
  int row0 = blockIdx.x * 64 + wv * 16;
  int gm = row0 + m;
  bool valid = gm < NN;
  if (!valid) gm = 0;
  short* band = &sT[wv][0];

  // hoist dependent index chain + own h-row so these gathers overlap Phase E
  int s = A.nidx[gm];
  int rv = A.root[s];
  int rt = A.tr[gm];
  const unsigned short* hrow = &A.hb[(size_t)gm * 64];
  uint4 hq0 = *(const uint4*)&hrow[q * 8];
  uint4 hq1 = *(const uint4*)&hrow[32 + q * 8];

  // ---- Phase E: edge aggregation for this wave's 16 rows (lane = channel) ----
  {
    int d = lane;
    float w[8];
#pragma unroll
    for (int k = 0; k < 8; k++) w[k] = A.We[k * 64 + d];
    float bed = A.be[d];
    for (int rr = 0; rr < 16; rr++) {
      int v = row0 + rr;
      if (v >= NN) v = 0;
      int base = A.eoff[v], deg = A.ecnt[v];
      float acc = 0.0f;
      int i = 0;
      for (; i + 4 <= deg; i += 4) {
        int s0 = A.ssrc[base + i + 0];
        int s1 = A.ssrc[base + i + 1];
        int s2 = A.ssrc[base + i + 2];
        int s3 = A.ssrc[base + i + 3];
        unsigned short g0 = A.hb[(size_t)s0 * 64 + d];
        unsigned short g1 = A.hb[(size_t)s1 * 64 + d];
        unsigned short g2 = A.hb[(size_t)s2 * 64 + d];
        unsigned short g3 = A.hb[(size_t)s3 * 64 + d];
        uint4 a0 = *(const uint4*)&A.eas[(size_t)(base + i + 0) * 8];
        uint4 a1 = *(const uint4*)&A.eas[(size_t)(base + i + 1) * 8];
        uint4 a2 = *(const uint4*)&A.eas[(size_t)(base + i + 2) * 8];
        uint4 a3 = *(const uint4*)&A.eas[(size_t)(base + i + 3) * 8];
        float e0 = bed + bfl(a0.x) * w[0] + bfh(a0.x) * w[1] + bfl(a0.y) * w[2] + bfh(a0.y) * w[3] +
                   bfl(a0.z) * w[4] + bfh(a0.z) * w[5] + bfl(a0.w) * w[6] + bfh(a0.w) * w[7];
        float e1 = bed + bfl(a1.x) * w[0] + bfh(a1.x) * w[1] + bfl(a1.y) * w[2] + bfh(a1.y) * w[3] +
                   bfl(a1.z) * w[4] + bfh(a1.z) * w[5] + bfl(a1.w) * w[6] + bfh(a1.w) * w[7];
        float e2 = bed + bfl(a2.x) * w[0] + bfh(a2.x) * w[1] + bfl(a2.y) * w[2] + bfh(a2.y) * w[3] +
                   bfl(a2.z) * w[4] + bfh(a2.z) * w[5] + bfl(a2.w) * w[6] + bfh(a2.w) * w[7];
        float e3 = bed + bfl(a3.x) * w[0] + bfh(a3.x) * w[1] + bfl(a3.y) * w[2] + bfh(a3.y) * w[3] +
                   bfl(a3.z) * w[4] + bfh(a3.z) * w[5] + bfl(a3.w) * w[6] + bfh(a3.w) * w[7];
        float m0 = bfu(g0) + e0;
        float m1 = bfu(g1) + e1;
        float m2 = bfu(g2) + e2;
        float m3 = bfu(g3) + e3;
        acc += (m0 > 0.0f ? m0 : 0.0f) + (m1 > 0.0f ? m1 : 0.0f) +
               (m2 > 0.0f ? m2 : 0.0f) + (m3 > 0.0f ? m3 : 0.0f);
      }
      for (; i < deg; i++) {
        int s0 = A.ssrc[base + i];
        unsigned short g0 = A.hb[(size_t)s0 * 64 + d];
        uint4 a0 = *(const uint4*)&A.eas[(size_t)(base + i) * 8];
        float e0 = bed + bfl(a0.x) * w[0] + bfh(a0.x) * w[1] + bfl(a0.y) * w[2] + bfh(a0.y) * w[3] +
                   bfl(a0.z) * w[4] + bfh(a0.z) * w[5] + bfl(a0.w) * w[6] + bfh(a0.w) * w[7];
        float m0 = bfu(g0) + e0;
        acc += m0 > 0.0f ? m0 : 0.0f;
      }
      band[rr * LDH + d] = f2bf(acc);  // agg row rr, channel d
    }
  }

  // ---- Phase M: 4 branches of MLP+LN (lane = (m,q) fragment role) ----
  float hacc[4][4];
#pragma unroll
  for (int i = 0; i < 4; i++)
#pragma unroll
    for (int j = 0; j < 4; j++) hacc[i][j] = 0.0f;

#pragma unroll 1
  for (int b = 0; b < 4; b++) {
    float aeps = 1.0f + A.eps[b][0];
    float hv[8], hw[8];
    unp8(hq0, hv);
    unp8(hq1, hw);
    float ov[8], ow[8];
    if (b == 0) {
      // agg from wave-local band (reads complete before GEMM1's T-writes: DS in-order)
      uint4 o0 = *(const uint4*)&band[m * LDH + q * 8];
      uint4 o1 = *(const uint4*)&band[m * LDH + 32 + q * 8];
      unp8(o0, ov);
      unp8(o1, ow);
    } else {
      const unsigned short* r0 = (b == 1) ? &A.hb[(size_t)rv * 64]
                               : (b == 2) ? &A.hb[(size_t)rt * 64]
                                          : &A.gsumb[(size_t)s * 64];
      uint4 o0 = *(const uint4*)&r0[q * 8];
      uint4 o1 = *(const uint4*)&r0[32 + q * 8];
      unp8(o0, ov);
      unp8(o1, ow);
    }

    union { bf16x8 v; uint4 u; } a0u, a1u;
    a0u.u.x = pack2(aeps * hv[0] + ov[0], aeps * hv[1] + ov[1]);
    a0u.u.y = pack2(aeps * hv[2] + ov[2], aeps * hv[3] + ov[3]);
    a0u.u.z = pack2(aeps * hv[4] + ov[4], aeps * hv[5] + ov[5]);
    a0u.u.w = pack2(aeps * hv[6] + ov[6], aeps * hv[7] + ov[7]);
    a1u.u.x = pack2(aeps * hw[0] + ow[0], aeps * hw[1] + ow[1]);
    a1u.u.y = pack2(aeps * hw[2] + ow[2], aeps * hw[3] + ow[3]);
    a1u.u.z = pack2(aeps * hw[4] + ow[4], aeps * hw[5] + ow[5]);
    a1u.u.w = pack2(aeps * hw[6] + ow[6], aeps * hw[7] + ow[7]);

    const short* w1 = A.wt1[b];
    const short* w2 = A.wt2[b];
    const float* b1p = A.b1[b];
    const float* b2p = A.b2[b];

    // GEMM1: T = relu(U @ W1 + b1) -> band (wave-local)
#pragma unroll
    for (int t = 0; t < 4; t++) {
      int n = t * 16 + m;
      bf16x8 w0 = *(const bf16x8*)&w1[n * 64 + q * 8];
      bf16x8 wk = *(const bf16x8*)&w1[n * 64 + 32 + q * 8];
      float bv = b1p[n];
      f32x4 c = {bv, bv, bv, bv};
      c = __builtin_amdgcn_mfma_f32_16x16x32_bf16(a0u.v, w0, c, 0, 0, 0);
      c = __builtin_amdgcn_mfma_f32_16x16x32_bf16(a1u.v, wk, c, 0, 0, 0);
#pragma unroll
      for (int r = 0; r < 4; r++) {
        float v = c[r];
        v = v > 0.0f ? v : 0.0f;
        band[(q * 4 + r) * LDH + n] = f2bf(v);
      }
    }

    bf16x8 t0 = *(const bf16x8*)&band[m * LDH + q * 8];
    bf16x8 t1 = *(const bf16x8*)&band[m * LDH + 32 + q * 8];

    // GEMM2: V = T @ W2 + b2
    f32x4 c2[4];
#pragma unroll
    for (int t = 0; t < 4; t++) {
      int n = t * 16 + m;
      bf16x8 w0 = *(const bf16x8*)&w2[n * 64 + q * 8];
      bf16x8 wk = *(const bf16x8*)&w2[n * 64 + 32 + q * 8];
      float bv = b2p[n];
      f32x4 c = {bv, bv, bv, bv};
      c = __builtin_amdgcn_mfma_f32_16x16x32_bf16(t0, w0, c, 0, 0, 0);
      c = __builtin_amdgcn_mfma_f32_16x16x32_bf16(t1, wk, c, 0, 0, 0);
      c2[t] = c;
    }

    // LayerNorm per row
    const float* ga = A.ga[b];
    const float* bbp = A.bb[b];
    float gav[4], bbv[4];
#pragma unroll
    for (int t = 0; t < 4; t++) {
      gav[t] = ga[t * 16 + m];
      bbv[t] = bbp[t * 16 + m];
    }
#pragma unroll
    for (int r = 0; r < 4; r++) {
      float s1 = c2[0][r] + c2[1][r] + c2[2][r] + c2[3][r];
      float s2 = c2[0][r] * c2[0][r] + c2[1][r] * c2[1][r] +
                 c2[2][r] * c2[2][r] + c2[3][r] * c2[3][r];
#pragma unroll
      for (int o = 1; o < 16; o <<= 1) {
        s1 += __shfl_xor(s1, o);
        s2 += __shfl_xor(s2, o);
      }
      float mu = s1 * (1.0f / 64.0f);
      float var = s2 * (1.0f / 64.0f) - mu * mu;
      float rr = rsqrtf(var + 1e-5f);
#pragma unroll
      for (int t = 0; t < 4; t++)
        hacc[r][t] += (c2[t][r] - mu) * rr * gav[t] + bbv[t];
    }
  }

  // epilogue: LDS roundtrip to coalesce bf16 stores (2x16B per lane)
#pragma unroll
  for (int r = 0; r < 4; r++)
#pragma unroll
    for (int t = 0; t < 4; t++)
      band[(q * 4 + r) * LDH + t * 16 + m] = f2bf(hacc[r][t]);
  if (valid) {
    uint4 v0 = *(const uint4*)&band[m * LDH + q * 8];
    uint4 v1 = *(const uint4*)&band[m * LDH + 32 + q * 8];
    unsigned short* orow = &A.hbout[(size_t)gm * 64];
    *(uint4*)&orow[q * 8] = v0;
    *(uint4*)&orow[32 + q * 8] = v1;
  }
}

// ---------------- fused final pooling + decoder ----------------
__global__ __launch_bounds__(256) void k_pool_out(const unsigned short* __restrict__ hb,
                                                  const int* __restrict__ nsorted,
                                                  const int* __restrict__ noff,
                                                  const int* __restrict__ ncnt,
                                                  const float* __restrict__ W,
                                                  const float* __restrict__ bjk,
                                                  float* __restrict__ out) {
  __shared__ float red[256];
  __shared__ float pr[64];
  int s = blockIdx.x, tid = threadIdx.x;
  int ch = tid & 63, r = tid >> 6;
  int base = noff[s], c = ncnt[s];
  float acc = 0.0f;
  int i = r;
  for (; i + 12 < c; i += 16) {
    int n0 = nsorted[base + i];
    int n1 = nsorted[base + i + 4];
    int n2 = nsorted[base + i + 8];
    int n3 = nsorted[base + i + 12];
    acc += bfu(hb[(size_t)n0 * 64 + ch]) + bfu(hb[(size_t)n1 * 64 + ch]) +
           bfu(hb[(size_t)n2 * 64 + ch]) + bfu(hb[(size_t)n3 * 64 + ch]);
  }
  for (; i < c; i += 4) acc += bfu(hb[(size_t)nsorted[base + i] * 64 + ch]);
  red[tid] = acc;
  __syncthreads();
  if (r == 0) pr[ch] = red[ch] + red[64 + ch] + red[128 + ch] + red[192 + ch];
  __syncthreads();
  if (tid < 64) {
    float o = bjk[tid];
#pragma unroll 8
    for (int k = 0; k < 64; k++) o += pr[k] * W[k * 64 + tid];
    out[s * 64 + tid] = o;
  }
}

extern "C" void kernel_launch(void* const* d_in, const int* in_sizes, int n_in,
                              void* d_out, int out_size, void* d_ws, size_t ws_size,
                              hipStream_t stream) {
  const float* x = (const float*)d_in[0];
  const float* edge_attr = (const float*)d_in[1];
  const int* edge_index = (const int*)d_in[2];
  const int* node_idx = (const int*)d_in[3];
  const int* root_idx = (const int*)d_in[4];
  const int* transpose_idx = (const int*)d_in[5];
  const float* W_init = (const float*)d_in[6];
  const float* b_init = (const float*)d_in[7];
  const float* lu_We = (const float*)d_in[8];
  const float* lu_be = (const float*)d_in[9];
  const float* eps_[4] = {(const float*)d_in[10], (const float*)d_in[17],
                          (const float*)d_in[24], (const float*)d_in[31]};
  const float* W1_[4] = {(const float*)d_in[11], (const float*)d_in[18],
                         (const float*)d_in[25], (const float*)d_in[32]};
  const float* b1_[4] = {(const float*)d_in[12], (const float*)d_in[19],
                         (const float*)d_in[26], (const float*)d_in[33]};
  const float* W2_[4] = {(const float*)d_in[13], (const float*)d_in[20],
                         (const float*)d_in[27], (const float*)d_in[34]};
  const float* b2_[4] = {(const float*)d_in[14], (const float*)d_in[21],
                         (const float*)d_in[28], (const float*)d_in[35]};
  const float* ga_[4] = {(const float*)d_in[15], (const float*)d_in[22],
                         (const float*)d_in[29], (const float*)d_in[36]};
  const float* bn_[4] = {(const float*)d_in[16], (const float*)d_in[23],
                         (const float*)d_in[30], (const float*)d_in[37]};
  const float* W_jk = (const float*)d_in[38];
  const float* b_jk = (const float*)d_in[39];

  // ---- workspace carve (~90 MB) ----
  char* p = (char*)d_ws;
  auto carve = [&](size_t bytes) -> char* {
    char* r = p;
    p += (bytes + 255) & ~(size_t)255;
    return r;
  };
  unsigned short* hb0 = (unsigned short*)carve((size_t)NN * DD * 2);  // 32 MB
  unsigned short* hb1 = (unsigned short*)carve((size_t)NN * DD * 2);  // 32 MB
  unsigned short* gsumb = (unsigned short*)carve(SS * DD * 2);
  float* cinv = (float*)carve(SS * 4);
  short* wbt = (short*)carve(24 * 4096 * 2);
  int* ecnt = (int*)carve(NN * 4);
  int* eoff = (int*)carve(NN * 4);
  int* ecurs = (int*)carve(NN * 4);
  int* ebsum = (int*)carve(256 * 4);
  int* ssrc = (int*)carve((size_t)EE * 4);                             // 4 MB
  unsigned short* eas = (unsigned short*)carve((size_t)EE * FEE * 2);  // 16 MB
  int* ncnt = (int*)carve(SS * 4);
  int* noff = (int*)carve(SS * 4);
  int* ncurs = (int*)carve(SS * 4);
  int* nbsum = (int*)carve(256 * 4);
  int* nsorted = (int*)carve(NN * 4);

  const int* srcp = edge_index;
  const int* dstp = edge_index + EE;

  // ---- build CSRs (identical work every call; graph-capture safe) ----
  hipMemsetAsync(ecnt, 0, NN * 4, stream);
  hipMemsetAsync(ncnt, 0, SS * 4, stream);
  k_hist<<<(EE + 255) / 256, 256, 0, stream>>>(dstp, ecnt, EE);
  k_hist<<<(NN + 255) / 256, 256, 0, stream>>>(node_idx, ncnt, NN);
  k_scan1<<<SNB, 256, 0, stream>>>(ecnt, eoff, ecurs, ebsum, NN);
  k_scan2<<<1, 256, 0, stream>>>(ebsum, SNB);
  k_scan3<<<SNB, 256, 0, stream>>>(eoff, ecurs, ebsum, NN);
  k_scan1<<<1, 256, 0, stream>>>(ncnt, noff, ncurs, nbsum, SS);
  k_bucket_e<<<(EE + 255) / 256, 256, 0, stream>>>(srcp, dstp, edge_attr, ecurs, ssrc, eas);
  k_bucket_n<<<(NN + 255) / 256, 256, 0, stream>>>(node_idx, ncurs, nsorted);
  k_cinv<<<(SS + 255) / 256, 256, 0, stream>>>(ncnt, cinv);

  k_init<<<(NN * DD) / 256, 256, 0, stream>>>(x, W_init, b_init, hb0);

  WPrep P;
  for (int b = 0; b < 4; b++) {
    P.W[b * 2 + 0] = W1_[b];
    P.W[b * 2 + 1] = W2_[b];
  }
  k_wprep<<<(24 * 4096) / 256, 256, 0, stream>>>(P, wbt);

  unsigned short* hbc = hb0;
  unsigned short* hbn = hb1;
  for (int l = 0; l < NL; l++) {
    k_gmean<<<SS, 256, 0, stream>>>(hbc, nsorted, noff, ncnt, cinv, gsumb);

    NodeArgs A;
    A.hb = hbc; A.gsumb = gsumb;
    A.eas = eas; A.ssrc = ssrc; A.eoff = eoff; A.ecnt = ecnt;
    A.We = lu_We + (size_t)l * FEE * DD;
    A.be = lu_be + l * DD;
    A.nidx = node_idx; A.root = root_idx; A.tr = transpose_idx;
    for (int b = 0; b < 4; b++) {
      A.eps[b] = eps_[b] + l;
      A.wt1[b] = wbt + ((size_t)(b * 2 + 0) * NL + l) * 4096;
      A.wt2[b] = wbt + ((size_t)(b * 2 + 1) * NL + l) * 4096;
      A.b1[b] = b1_[b] + l * DD;
      A.b2[b] = b2_[b] + l * DD;
      A.ga[b] = ga_[b] + l * DD;
      A.bb[b] = bn_[b] + l * DD;
    }
    A.hbout = hbn;
    k_node<<<(NN + 63) / 64, 256, 0, stream>>>(A);
    unsigned short* tmpb = hbc; hbc = hbn; hbn = tmpb;
  }

  k_pool_out<<<SS, 256, 0, stream>>>(hbc, nsorted, noff, ncnt, W_jk, b_jk, (float*)d_out);
}

// Round 11
// 1196.557 us; speedup vs baseline: 1.0753x; 1.0753x over previous
//
#include <hip/hip_runtime.h>

#define NN 250000
#define EE 1000000
#define SS 1000
#define DD 64
#define FIN 16
#define FEE 8
#define NL 3
#define LDH 72  // band row stride (bf16 elems); 144B row -> 2-way bank alias (free)
#define SCHUNK 1024
#define SNB ((NN + SCHUNK - 1) / SCHUNK)  // 245

typedef __attribute__((ext_vector_type(8))) short bf16x8;
typedef __attribute__((ext_vector_type(4))) float f32x4;

static __device__ __forceinline__ short f2bf(float f) {
  union { float f; unsigned u; } v{f};
  unsigned r = (v.u + 0x7fffu + ((v.u >> 16) & 1u)) >> 16;  // RNE
  return (short)r;
}
static __device__ __forceinline__ float bfl(unsigned u) {
  union { unsigned u; float f; } v{u << 16};
  return v.f;
}
static __device__ __forceinline__ float bfh(unsigned u) {
  union { unsigned u; float f; } v{u & 0xffff0000u};
  return v.f;
}
static __device__ __forceinline__ float bfu(unsigned short u) {
  union { unsigned u; float f; } v{(unsigned)u << 16};
  return v.f;
}
static __device__ __forceinline__ unsigned pack2(float a, float b) {
  return (unsigned)(unsigned short)f2bf(a) | ((unsigned)(unsigned short)f2bf(b) << 16);
}
static __device__ __forceinline__ void unp8(uint4 v, float* o) {
  o[0] = bfl(v.x); o[1] = bfh(v.x); o[2] = bfl(v.y); o[3] = bfh(v.y);
  o[4] = bfl(v.z); o[5] = bfh(v.z); o[6] = bfl(v.w); o[7] = bfh(v.w);
}

// ---------------- histogram ----------------
__global__ __launch_bounds__(256) void k_hist(const int* __restrict__ idx,
                                              int* __restrict__ cnt, int n) {
  int i = blockIdx.x * 256 + threadIdx.x;
  if (i < n) atomicAdd(&cnt[idx[i]], 1);
}

// ---------------- block-local exclusive scan (chunk=1024) ----------------
__global__ __launch_bounds__(256) void k_scan1(const int* __restrict__ cntv,
                                               int* __restrict__ off,
                                               int* __restrict__ curs,
                                               int* __restrict__ bsums, int n) {
  __shared__ int ls[256];
  int b = blockIdx.x, t = threadIdx.x;
  int base = b * SCHUNK + t * 4;
  int v[4];
#pragma unroll
  for (int j = 0; j < 4; j++) v[j] = (base + j < n) ? cntv[base + j] : 0;
  int s4 = v[0] + v[1] + v[2] + v[3];
  ls[t] = s4;
  __syncthreads();
  for (int o = 1; o < 256; o <<= 1) {
    int x = (t >= o) ? ls[t - o] : 0;
    __syncthreads();
    ls[t] += x;
    __syncthreads();
  }
  int run = ls[t] - s4;
#pragma unroll
  for (int j = 0; j < 4; j++) {
    if (base + j < n) { off[base + j] = run; curs[base + j] = run; }
    run += v[j];
  }
  if (t == 255) bsums[b] = ls[255];
}

__global__ __launch_bounds__(256) void k_scan2(int* __restrict__ bsums, int nb) {
  __shared__ int ls[256];
  int t = threadIdx.x;
  int v = (t < nb) ? bsums[t] : 0;
  ls[t] = v;
  __syncthreads();
  for (int o = 1; o < 256; o <<= 1) {
    int x = (t >= o) ? ls[t - o] : 0;
    __syncthreads();
    ls[t] += x;
    __syncthreads();
  }
  if (t < nb) bsums[t] = ls[t] - v;  // exclusive
}

__global__ __launch_bounds__(256) void k_scan3(int* __restrict__ off,
                                               int* __restrict__ curs,
                                               const int* __restrict__ bsums, int n) {
  int b = blockIdx.x, t = threadIdx.x;
  int add = bsums[b];
  int base = b * SCHUNK + t * 4;
#pragma unroll
  for (int j = 0; j < 4; j++)
    if (base + j < n) { off[base + j] += add; curs[base + j] += add; }
}

// ---------------- bucket scatter: src + bf16 edge-attrs in CSR order ----------------
__global__ __launch_bounds__(256) void k_bucket_e(const int* __restrict__ src,
                                                  const int* __restrict__ dst,
                                                  const float* __restrict__ ea,
                                                  int* __restrict__ curs,
                                                  int* __restrict__ ssrc,
                                                  unsigned short* __restrict__ eas) {
  int e = blockIdx.x * 256 + threadIdx.x;
  if (e >= EE) return;
  int pos = atomicAdd(&curs[dst[e]], 1);
  ssrc[pos] = src[e];
  const float* a = &ea[(size_t)e * 8];
  uint4 p;
  p.x = pack2(a[0], a[1]);
  p.y = pack2(a[2], a[3]);
  p.z = pack2(a[4], a[5]);
  p.w = pack2(a[6], a[7]);
  *(uint4*)&eas[(size_t)pos * 8] = p;
}

__global__ __launch_bounds__(256) void k_bucket_n(const int* __restrict__ nidx,
                                                  int* __restrict__ curs,
                                                  int* __restrict__ nsorted) {
  int n = blockIdx.x * 256 + threadIdx.x;
  if (n >= NN) return;
  int pos = atomicAdd(&curs[nidx[n]], 1);
  nsorted[pos] = n;
}

__global__ __launch_bounds__(256) void k_cinv(const int* __restrict__ ncnt,
                                              float* __restrict__ cinv) {
  int s = blockIdx.x * 256 + threadIdx.x;
  if (s < SS) {
    float c = (float)ncnt[s];
    cinv[s] = 1.0f / (c < 1.0f ? 1.0f : c);
  }
}

// ---------------- init encoder: hb = bf16(x @ W_init + b) ----------------
__global__ __launch_bounds__(256) void k_init(const float* __restrict__ x,
                                              const float* __restrict__ W,
                                              const float* __restrict__ b,
                                              unsigned short* __restrict__ hb) {
  int gid = blockIdx.x * 256 + threadIdx.x;
  int n = gid >> 6, d = gid & 63;
  const float* xr = x + (size_t)n * FIN;
  float acc = b[d];
#pragma unroll
  for (int k = 0; k < FIN; k++) acc += xr[k] * W[k * DD + d];
  hb[gid] = (unsigned short)f2bf(acc);
}

// ---------------- weight prep: bf16 W^T ----------------
struct WPrep { const float* W[8]; };

__global__ __launch_bounds__(256) void k_wprep(WPrep P, short* __restrict__ wbt) {
  int gid = blockIdx.x * 256 + threadIdx.x;  // 24*4096
  int slot = gid >> 12;
  int e = gid & 4095;
  int n = e >> 6, k = e & 63;
  int bg = slot / NL, l = slot % NL;
  float v = P.W[bg][(size_t)l * 4096 + k * 64 + n];
  wbt[gid] = f2bf(v);
}

// ---------------- segment mean (bf16 out) ----------------
__global__ __launch_bounds__(256) void k_gmean(const unsigned short* __restrict__ hb,
                                               const int* __restrict__ nsorted,
                                               const int* __restrict__ noff,
                                               const int* __restrict__ ncnt,
                                               const float* __restrict__ cinv,
                                               unsigned short* __restrict__ gsumb) {
  __shared__ float red[256];
  int s = blockIdx.x;
  int tid = threadIdx.x;
  int ch = tid & 63, r = tid >> 6;
  int base = noff[s], c = ncnt[s];
  float acc = 0.0f;
  int i = r;
  for (; i + 12 < c; i += 16) {
    int n0 = nsorted[base + i];
    int n1 = nsorted[base + i + 4];
    int n2 = nsorted[base + i + 8];
    int n3 = nsorted[base + i + 12];
    acc += bfu(hb[(size_t)n0 * 64 + ch]) + bfu(hb[(size_t)n1 * 64 + ch]) +
           bfu(hb[(size_t)n2 * 64 + ch]) + bfu(hb[(size_t)n3 * 64 + ch]);
  }
  for (; i < c; i += 4) acc += bfu(hb[(size_t)nsorted[base + i] * 64 + ch]);
  red[tid] = acc;
  __syncthreads();
  if (r == 0) {
    float vsum = red[ch] + red[64 + ch] + red[128 + ch] + red[192 + ch];
    gsumb[s * 64 + ch] = (unsigned short)f2bf(vsum * cinv[s]);
  }
}

// ---------------- fused node kernel: edge-agg + 4x(MLP+LN), wave-autonomous ----------------
struct NodeArgs {
  const unsigned short* hb;
  const unsigned short* gsumb;
  const unsigned short* eas;
  const int* ssrc;
  const int* eoff;
  const int* ecnt;
  const float* We;
  const float* be;
  const int* nidx;
  const int* root;
  const int* tr;
  const float* eps[4];
  const short* wt1[4];
  const short* wt2[4];
  const float* b1[4];
  const float* b2[4];
  const float* ga[4];
  const float* bb[4];
  unsigned short* hbout;
};

// Register-demand ladder (measured): (256,4)=no spill @ ~128 budget,
// (256,6)=spill @ 85, (256,8)=heavy spill @ 64 -> true demand in (85,128].
// (256,5) gives budget 512/5~=102; plus h-row reload moved inside branch loop
// (kills an 8-reg live range across Phase E). Expect no spill at 62.5% occ cap.
__global__ __launch_bounds__(256, 5) void k_node(NodeArgs A) {
  __shared__ short sT[4][16 * LDH];  // per-wave band (DS ops are wave-in-order: no barriers)
  int tid = threadIdx.x;
  int wv = tid >> 6;
  int lane = tid & 63;
  int m = lane & 15, q = lane >> 4;
  int row0 = blockIdx.x * 64 + wv * 16;
  int gm = row0 + m;
  bool valid = gm < NN;
  if (!valid) gm = 0;
  short* band = &sT[wv][0];

  // hoist only the dependent index chain (3 ints) to overlap Phase E
  int s = A.nidx[gm];
  int rv = A.root[s];
  int rt = A.tr[gm];

  // ---- Phase E: edge aggregation for this wave's 16 rows (lane = channel) ----
  {
    int d = lane;
    float w[8];
#pragma unroll
    for (int k = 0; k < 8; k++) w[k] = A.We[k * 64 + d];
    float bed = A.be[d];
    for (int rr = 0; rr < 16; rr++) {
      int v = row0 + rr;
      if (v >= NN) v = 0;
      int base = A.eoff[v], deg = A.ecnt[v];
      float acc = 0.0f;
      int i = 0;
      for (; i + 4 <= deg; i += 4) {
        int s0 = A.ssrc[base + i + 0];
        int s1 = A.ssrc[base + i + 1];
        int s2 = A.ssrc[base + i + 2];
        int s3 = A.ssrc[base + i + 3];
        unsigned short g0 = A.hb[(size_t)s0 * 64 + d];
        unsigned short g1 = A.hb[(size_t)s1 * 64 + d];
        unsigned short g2 = A.hb[(size_t)s2 * 64 + d];
        unsigned short g3 = A.hb[(size_t)s3 * 64 + d];
        uint4 a0 = *(const uint4*)&A.eas[(size_t)(base + i + 0) * 8];
        uint4 a1 = *(const uint4*)&A.eas[(size_t)(base + i + 1) * 8];
        uint4 a2 = *(const uint4*)&A.eas[(size_t)(base + i + 2) * 8];
        uint4 a3 = *(const uint4*)&A.eas[(size_t)(base + i + 3) * 8];
        float e0 = bed + bfl(a0.x) * w[0] + bfh(a0.x) * w[1] + bfl(a0.y) * w[2] + bfh(a0.y) * w[3] +
                   bfl(a0.z) * w[4] + bfh(a0.z) * w[5] + bfl(a0.w) * w[6] + bfh(a0.w) * w[7];
        float e1 = bed + bfl(a1.x) * w[0] + bfh(a1.x) * w[1] + bfl(a1.y) * w[2] + bfh(a1.y) * w[3] +
                   bfl(a1.z) * w[4] + bfh(a1.z) * w[5] + bfl(a1.w) * w[6] + bfh(a1.w) * w[7];
        float e2 = bed + bfl(a2.x) * w[0] + bfh(a2.x) * w[1] + bfl(a2.y) * w[2] + bfh(a2.y) * w[3] +
                   bfl(a2.z) * w[4] + bfh(a2.z) * w[5] + bfl(a2.w) * w[6] + bfh(a2.w) * w[7];
        float e3 = bed + bfl(a3.x) * w[0] + bfh(a3.x) * w[1] + bfl(a3.y) * w[2] + bfh(a3.y) * w[3] +
                   bfl(a3.z) * w[4] + bfh(a3.z) * w[5] + bfl(a3.w) * w[6] + bfh(a3.w) * w[7];
        float m0 = bfu(g0) + e0;
        float m1 = bfu(g1) + e1;
        float m2 = bfu(g2) + e2;
        float m3 = bfu(g3) + e3;
        acc += (m0 > 0.0f ? m0 : 0.0f) + (m1 > 0.0f ? m1 : 0.0f) +
               (m2 > 0.0f ? m2 : 0.0f) + (m3 > 0.0f ? m3 : 0.0f);
      }
      for (; i < deg; i++) {
        int s0 = A.ssrc[base + i];
        unsigned short g0 = A.hb[(size_t)s0 * 64 + d];
        uint4 a0 = *(const uint4*)&A.eas[(size_t)(base + i) * 8];
        float e0 = bed + bfl(a0.x) * w[0] + bfh(a0.x) * w[1] + bfl(a0.y) * w[2] + bfh(a0.y) * w[3] +
                   bfl(a0.z) * w[4] + bfh(a0.z) * w[5] + bfl(a0.w) * w[6] + bfh(a0.w) * w[7];
        float m0 = bfu(g0) + e0;
        acc += m0 > 0.0f ? m0 : 0.0f;
      }
      band[rr * LDH + d] = f2bf(acc);  // agg row rr, channel d
    }
  }

  // ---- Phase M: 4 branches of MLP+LN (lane = (m,q) fragment role) ----
  float hacc[4][4];
#pragma unroll
  for (int i = 0; i < 4; i++)
#pragma unroll
    for (int j = 0; j < 4; j++) hacc[i][j] = 0.0f;

#pragma unroll 1
  for (int b = 0; b < 4; b++) {
    float aeps = 1.0f + A.eps[b][0];
    // own h-row reloaded each branch (L1/L2-hot; short live range beats 8 held regs)
    const unsigned short* hrow = &A.hb[(size_t)gm * 64];
    uint4 hq0 = *(const uint4*)&hrow[q * 8];
    uint4 hq1 = *(const uint4*)&hrow[32 + q * 8];
    float hv[8], hw[8];
    unp8(hq0, hv);
    unp8(hq1, hw);
    float ov[8], ow[8];
    if (b == 0) {
      // agg from wave-local band (reads complete before GEMM1's T-writes: DS in-order)
      uint4 o0 = *(const uint4*)&band[m * LDH + q * 8];
      uint4 o1 = *(const uint4*)&band[m * LDH + 32 + q * 8];
      unp8(o0, ov);
      unp8(o1, ow);
    } else {
      const unsigned short* r0 = (b == 1) ? &A.hb[(size_t)rv * 64]
                               : (b == 2) ? &A.hb[(size_t)rt * 64]
                                          : &A.gsumb[(size_t)s * 64];
      uint4 o0 = *(const uint4*)&r0[q * 8];
      uint4 o1 = *(const uint4*)&r0[32 + q * 8];
      unp8(o0, ov);
      unp8(o1, ow);
    }

    union { bf16x8 v; uint4 u; } a0u, a1u;
    a0u.u.x = pack2(aeps * hv[0] + ov[0], aeps * hv[1] + ov[1]);
    a0u.u.y = pack2(aeps * hv[2] + ov[2], aeps * hv[3] + ov[3]);
    a0u.u.z = pack2(aeps * hv[4] + ov[4], aeps * hv[5] + ov[5]);
    a0u.u.w = pack2(aeps * hv[6] + ov[6], aeps * hv[7] + ov[7]);
    a1u.u.x = pack2(aeps * hw[0] + ow[0], aeps * hw[1] + ow[1]);
    a1u.u.y = pack2(aeps * hw[2] + ow[2], aeps * hw[3] + ow[3]);
    a1u.u.z = pack2(aeps * hw[4] + ow[4], aeps * hw[5] + ow[5]);
    a1u.u.w = pack2(aeps * hw[6] + ow[6], aeps * hw[7] + ow[7]);

    const short* w1 = A.wt1[b];
    const short* w2 = A.wt2[b];
    const float* b1p = A.b1[b];
    const float* b2p = A.b2[b];

    // GEMM1: T = relu(U @ W1 + b1) -> band (wave-local)
#pragma unroll
    for (int t = 0; t < 4; t++) {
      int n = t * 16 + m;
      bf16x8 w0 = *(const bf16x8*)&w1[n * 64 + q * 8];
      bf16x8 wk = *(const bf16x8*)&w1[n * 64 + 32 + q * 8];
      float bv = b1p[n];
      f32x4 c = {bv, bv, bv, bv};
      c = __builtin_amdgcn_mfma_f32_16x16x32_bf16(a0u.v, w0, c, 0, 0, 0);
      c = __builtin_amdgcn_mfma_f32_16x16x32_bf16(a1u.v, wk, c, 0, 0, 0);
#pragma unroll
      for (int r = 0; r < 4; r++) {
        float v = c[r];
        v = v > 0.0f ? v : 0.0f;
        band[(q * 4 + r) * LDH + n] = f2bf(v);
      }
    }

    bf16x8 t0 = *(const bf16x8*)&band[m * LDH + q * 8];
    bf16x8 t1 = *(const bf16x8*)&band[m * LDH + 32 + q * 8];

    // GEMM2: V = T @ W2 + b2
    f32x4 c2[4];
#pragma unroll
    for (int t = 0; t < 4; t++) {
      int n = t * 16 + m;
      bf16x8 w0 = *(const bf16x8*)&w2[n * 64 + q * 8];
      bf16x8 wk = *(const bf16x8*)&w2[n * 64 + 32 + q * 8];
      float bv = b2p[n];
      f32x4 c = {bv, bv, bv, bv};
      c = __builtin_amdgcn_mfma_f32_16x16x32_bf16(t0, w0, c, 0, 0, 0);
      c = __builtin_amdgcn_mfma_f32_16x16x32_bf16(t1, wk, c, 0, 0, 0);
      c2[t] = c;
    }

    // LayerNorm per row
    const float* ga = A.ga[b];
    const float* bbp = A.bb[b];
    float gav[4], bbv[4];
#pragma unroll
    for (int t = 0; t < 4; t++) {
      gav[t] = ga[t * 16 + m];
      bbv[t] = bbp[t * 16 + m];
    }
#pragma unroll
    for (int r = 0; r < 4; r++) {
      float s1 = c2[0][r] + c2[1][r] + c2[2][r] + c2[3][r];
      float s2 = c2[0][r] * c2[0][r] + c2[1][r] * c2[1][r] +
                 c2[2][r] * c2[2][r] + c2[3][r] * c2[3][r];
#pragma unroll
      for (int o = 1; o < 16; o <<= 1) {
        s1 += __shfl_xor(s1, o);
        s2 += __shfl_xor(s2, o);
      }
      float mu = s1 * (1.0f / 64.0f);
      float var = s2 * (1.0f / 64.0f) - mu * mu;
      float rr = rsqrtf(var + 1e-5f);
#pragma unroll
      for (int t = 0; t < 4; t++)
        hacc[r][t] += (c2[t][r] - mu) * rr * gav[t] + bbv[t];
    }
  }

  // epilogue: LDS roundtrip to coalesce bf16 stores (2x16B per lane)
#pragma unroll
  for (int r = 0; r < 4; r++)
#pragma unroll
    for (int t = 0; t < 4; t++)
      band[(q * 4 + r) * LDH + t * 16 + m] = f2bf(hacc[r][t]);
  if (valid) {
    uint4 v0 = *(const uint4*)&band[m * LDH + q * 8];
    uint4 v1 = *(const uint4*)&band[m * LDH + 32 + q * 8];
    unsigned short* orow = &A.hbout[(size_t)gm * 64];
    *(uint4*)&orow[q * 8] = v0;
    *(uint4*)&orow[32 + q * 8] = v1;
  }
}

// ---------------- fused final pooling + decoder ----------------
__global__ __launch_bounds__(256) void k_pool_out(const unsigned short* __restrict__ hb,
                                                  const int* __restrict__ nsorted,
                                                  const int* __restrict__ noff,
                                                  const int* __restrict__ ncnt,
                                                  const float* __restrict__ W,
                                                  const float* __restrict__ bjk,
                                                  float* __restrict__ out) {
  __shared__ float red[256];
  __shared__ float pr[64];
  int s = blockIdx.x, tid = threadIdx.x;
  int ch = tid & 63, r = tid >> 6;
  int base = noff[s], c = ncnt[s];
  float acc = 0.0f;
  int i = r;
  for (; i + 12 < c; i += 16) {
    int n0 = nsorted[base + i];
    int n1 = nsorted[base + i + 4];
    int n2 = nsorted[base + i + 8];
    int n3 = nsorted[base + i + 12];
    acc += bfu(hb[(size_t)n0 * 64 + ch]) + bfu(hb[(size_t)n1 * 64 + ch]) +
           bfu(hb[(size_t)n2 * 64 + ch]) + bfu(hb[(size_t)n3 * 64 + ch]);
  }
  for (; i < c; i += 4) acc += bfu(hb[(size_t)nsorted[base + i] * 64 + ch]);
  red[tid] = acc;
  __syncthreads();
  if (r == 0) pr[ch] = red[ch] + red[64 + ch] + red[128 + ch] + red[192 + ch];
  __syncthreads();
  if (tid < 64) {
    float o = bjk[tid];
#pragma unroll 8
    for (int k = 0; k < 64; k++) o += pr[k] * W[k * 64 + tid];
    out[s * 64 + tid] = o;
  }
}

extern "C" void kernel_launch(void* const* d_in, const int* in_sizes, int n_in,
                              void* d_out, int out_size, void* d_ws, size_t ws_size,
                              hipStream_t stream) {
  const float* x = (const float*)d_in[0];
  const float* edge_attr = (const float*)d_in[1];
  const int* edge_index = (const int*)d_in[2];
  const int* node_idx = (const int*)d_in[3];
  const int* root_idx = (const int*)d_in[4];
  const int* transpose_idx = (const int*)d_in[5];
  const float* W_init = (const float*)d_in[6];
  const float* b_init = (const float*)d_in[7];
  const float* lu_We = (const float*)d_in[8];
  const float* lu_be = (const float*)d_in[9];
  const float* eps_[4] = {(const float*)d_in[10], (const float*)d_in[17],
                          (const float*)d_in[24], (const float*)d_in[31]};
  const float* W1_[4] = {(const float*)d_in[11], (const float*)d_in[18],
                         (const float*)d_in[25], (const float*)d_in[32]};
  const float* b1_[4] = {(const float*)d_in[12], (const float*)d_in[19],
                         (const float*)d_in[26], (const float*)d_in[33]};
  const float* W2_[4] = {(const float*)d_in[13], (const float*)d_in[20],
                         (const float*)d_in[27], (const float*)d_in[34]};
  const float* b2_[4] = {(const float*)d_in[14], (const float*)d_in[21],
                         (const float*)d_in[28], (const float*)d_in[35]};
  const float* ga_[4] = {(const float*)d_in[15], (const float*)d_in[22],
                         (const float*)d_in[29], (const float*)d_in[36]};
  const float* bn_[4] = {(const float*)d_in[16], (const float*)d_in[23],
                         (const float*)d_in[30], (const float*)d_in[37]};
  const float* W_jk = (const float*)d_in[38];
  const float* b_jk = (const float*)d_in[39];

  // ---- workspace carve (~90 MB) ----
  char* p = (char*)d_ws;
  auto carve = [&](size_t bytes) -> char* {
    char* r = p;
    p += (bytes + 255) & ~(size_t)255;
    return r;
  };
  unsigned short* hb0 = (unsigned short*)carve((size_t)NN * DD * 2);  // 32 MB
  unsigned short* hb1 = (unsigned short*)carve((size_t)NN * DD * 2);  // 32 MB
  unsigned short* gsumb = (unsigned short*)carve(SS * DD * 2);
  float* cinv = (float*)carve(SS * 4);
  short* wbt = (short*)carve(24 * 4096 * 2);
  int* ecnt = (int*)carve(NN * 4);
  int* eoff = (int*)carve(NN * 4);
  int* ecurs = (int*)carve(NN * 4);
  int* ebsum = (int*)carve(256 * 4);
  int* ssrc = (int*)carve((size_t)EE * 4);                             // 4 MB
  unsigned short* eas = (unsigned short*)carve((size_t)EE * FEE * 2);  // 16 MB
  int* ncnt = (int*)carve(SS * 4);
  int* noff = (int*)carve(SS * 4);
  int* ncurs = (int*)carve(SS * 4);
  int* nbsum = (int*)carve(256 * 4);
  int* nsorted = (int*)carve(NN * 4);

  const int* srcp = edge_index;
  const int* dstp = edge_index + EE;

  // ---- build CSRs (identical work every call; graph-capture safe) ----
  hipMemsetAsync(ecnt, 0, NN * 4, stream);
  hipMemsetAsync(ncnt, 0, SS * 4, stream);
  k_hist<<<(EE + 255) / 256, 256, 0, stream>>>(dstp, ecnt, EE);
  k_hist<<<(NN + 255) / 256, 256, 0, stream>>>(node_idx, ncnt, NN);
  k_scan1<<<SNB, 256, 0, stream>>>(ecnt, eoff, ecurs, ebsum, NN);
  k_scan2<<<1, 256, 0, stream>>>(ebsum, SNB);
  k_scan3<<<SNB, 256, 0, stream>>>(eoff, ecurs, ebsum, NN);
  k_scan1<<<1, 256, 0, stream>>>(ncnt, noff, ncurs, nbsum, SS);
  k_bucket_e<<<(EE + 255) / 256, 256, 0, stream>>>(srcp, dstp, edge_attr, ecurs, ssrc, eas);
  k_bucket_n<<<(NN + 255) / 256, 256, 0, stream>>>(node_idx, ncurs, nsorted);
  k_cinv<<<(SS + 255) / 256, 256, 0, stream>>>(ncnt, cinv);

  k_init<<<(NN * DD) / 256, 256, 0, stream>>>(x, W_init, b_init, hb0);

  WPrep P;
  for (int b = 0; b < 4; b++) {
    P.W[b * 2 + 0] = W1_[b];
    P.W[b * 2 + 1] = W2_[b];
  }
  k_wprep<<<(24 * 4096) / 256, 256, 0, stream>>>(P, wbt);

  unsigned short* hbc = hb0;
  unsigned short* hbn = hb1;
  for (int l = 0; l < NL; l++) {
    k_gmean<<<SS, 256, 0, stream>>>(hbc, nsorted, noff, ncnt, cinv, gsumb);

    NodeArgs A;
    A.hb = hbc; A.gsumb = gsumb;
    A.eas = eas; A.ssrc = ssrc; A.eoff = eoff; A.ecnt = ecnt;
    A.We = lu_We + (size_t)l * FEE * DD;
    A.be = lu_be + l * DD;
    A.nidx = node_idx; A.root = root_idx; A.tr = transpose_idx;
    for (int b = 0; b < 4; b++) {
      A.eps[b] = eps_[b] + l;
      A.wt1[b] = wbt + ((size_t)(b * 2 + 0) * NL + l) * 4096;
      A.wt2[b] = wbt + ((size_t)(b * 2 + 1) * NL + l) * 4096;
      A.b1[b] = b1_[b] + l * DD;
      A.b2[b] = b2_[b] + l * DD;
      A.ga[b] = ga_[b] + l * DD;
      A.bb[b] = bn_[b] + l * DD;
    }
    A.hbout = hbn;
    k_node<<<(NN + 63) / 64, 256, 0, stream>>>(A);
    unsigned short* tmpb = hbc; hbc = hbn; hbn = tmpb;
  }

  k_pool_out<<<SS, 256, 0, stream>>>(hbc, nsorted, noff, ncnt, W_jk, b_jk, (float*)d_out);
}

// Round 12
// 1119.625 us; speedup vs baseline: 1.1492x; 1.0687x over previous
//
#include <hip/hip_runtime.h>

#define NN 250000
#define EE 1000000
#define SS 1000
#define DD 64
#define FIN 16
#define FEE 8
#define NL 3
#define LDH 72  // band row stride (bf16 elems); 144B row -> 2-way bank alias (free)
#define SCHUNK 1024
#define SNB ((NN + SCHUNK - 1) / SCHUNK)  // 245
#define EHB ((EE + 255) / 256)            // 3907
#define NHB ((NN + 255) / 256)            // 977

typedef __attribute__((ext_vector_type(8))) short bf16x8;
typedef __attribute__((ext_vector_type(4))) float f32x4;

static __device__ __forceinline__ short f2bf(float f) {
  union { float f; unsigned u; } v{f};
  unsigned r = (v.u + 0x7fffu + ((v.u >> 16) & 1u)) >> 16;  // RNE
  return (short)r;
}
static __device__ __forceinline__ float bfl(unsigned u) {
  union { unsigned u; float f; } v{u << 16};
  return v.f;
}
static __device__ __forceinline__ float bfh(unsigned u) {
  union { unsigned u; float f; } v{u & 0xffff0000u};
  return v.f;
}
static __device__ __forceinline__ float bfu(unsigned short u) {
  union { unsigned u; float f; } v{(unsigned)u << 16};
  return v.f;
}
static __device__ __forceinline__ unsigned pack2(float a, float b) {
  return (unsigned)(unsigned short)f2bf(a) | ((unsigned)(unsigned short)f2bf(b) << 16);
}
static __device__ __forceinline__ void unp8(uint4 v, float* o) {
  o[0] = bfl(v.x); o[1] = bfh(v.x); o[2] = bfl(v.y); o[3] = bfh(v.y);
  o[4] = bfl(v.z); o[5] = bfh(v.z); o[6] = bfl(v.w); o[7] = bfh(v.w);
}

// ---------------- fused histograms (edge-dst + node-seg) ----------------
__global__ __launch_bounds__(256) void k_hist2(const int* __restrict__ dstp,
                                               const int* __restrict__ nidx,
                                               int* __restrict__ ecnt,
                                               int* __restrict__ ncnt) {
  int b = blockIdx.x;
  if (b < EHB) {
    int i = b * 256 + threadIdx.x;
    if (i < EE) atomicAdd(&ecnt[dstp[i]], 1);
  } else {
    int i = (b - EHB) * 256 + threadIdx.x;
    if (i < NN) atomicAdd(&ncnt[nidx[i]], 1);
  }
}

// ---------------- block-local exclusive scan (chunk=1024), optional cinv ----------------
__global__ __launch_bounds__(256) void k_scan1(const int* __restrict__ cntv,
                                               int* __restrict__ off,
                                               int* __restrict__ curs,
                                               int* __restrict__ bsums, int n,
                                               float* __restrict__ cinv) {
  __shared__ int ls[256];
  int b = blockIdx.x, t = threadIdx.x;
  int base = b * SCHUNK + t * 4;
  int v[4];
#pragma unroll
  for (int j = 0; j < 4; j++) v[j] = (base + j < n) ? cntv[base + j] : 0;
  if (cinv) {
#pragma unroll
    for (int j = 0; j < 4; j++)
      if (base + j < n) cinv[base + j] = 1.0f / (float)(v[j] < 1 ? 1 : v[j]);
  }
  int s4 = v[0] + v[1] + v[2] + v[3];
  ls[t] = s4;
  __syncthreads();
  for (int o = 1; o < 256; o <<= 1) {
    int x = (t >= o) ? ls[t - o] : 0;
    __syncthreads();
    ls[t] += x;
    __syncthreads();
  }
  int run = ls[t] - s4;
#pragma unroll
  for (int j = 0; j < 4; j++) {
    if (base + j < n) { off[base + j] = run; curs[base + j] = run; }
    run += v[j];
  }
  if (t == 255) bsums[b] = ls[255];
}

__global__ __launch_bounds__(256) void k_scan2(int* __restrict__ bsums, int nb) {
  __shared__ int ls[256];
  int t = threadIdx.x;
  int v = (t < nb) ? bsums[t] : 0;
  ls[t] = v;
  __syncthreads();
  for (int o = 1; o < 256; o <<= 1) {
    int x = (t >= o) ? ls[t - o] : 0;
    __syncthreads();
    ls[t] += x;
    __syncthreads();
  }
  if (t < nb) bsums[t] = ls[t] - v;  // exclusive
}

__global__ __launch_bounds__(256) void k_scan3(int* __restrict__ off,
                                               int* __restrict__ curs,
                                               const int* __restrict__ bsums, int n) {
  int b = blockIdx.x, t = threadIdx.x;
  int add = bsums[b];
  int base = b * SCHUNK + t * 4;
#pragma unroll
  for (int j = 0; j < 4; j++)
    if (base + j < n) { off[base + j] += add; curs[base + j] += add; }
}

// ---------------- fused bucket scatter: edges (src + bf16 attrs) + nodes ----------------
__global__ __launch_bounds__(256) void k_bucket2(const int* __restrict__ src,
                                                 const int* __restrict__ dst,
                                                 const float* __restrict__ ea,
                                                 int* __restrict__ ecurs,
                                                 int* __restrict__ ssrc,
                                                 unsigned short* __restrict__ eas,
                                                 const int* __restrict__ nidx,
                                                 int* __restrict__ ncurs,
                                                 int* __restrict__ nsorted) {
  int b = blockIdx.x;
  if (b < EHB) {
    int e = b * 256 + threadIdx.x;
    if (e >= EE) return;
    int pos = atomicAdd(&ecurs[dst[e]], 1);
    ssrc[pos] = src[e];
    const float* a = &ea[(size_t)e * 8];
    uint4 p;
    p.x = pack2(a[0], a[1]);
    p.y = pack2(a[2], a[3]);
    p.z = pack2(a[4], a[5]);
    p.w = pack2(a[6], a[7]);
    *(uint4*)&eas[(size_t)pos * 8] = p;
  } else {
    int n = (b - EHB) * 256 + threadIdx.x;
    if (n >= NN) return;
    int pos = atomicAdd(&ncurs[nidx[n]], 1);
    nsorted[pos] = n;
  }
}

// ---------------- init encoder: hb = bf16(x @ W_init + b) ----------------
__global__ __launch_bounds__(256) void k_init(const float* __restrict__ x,
                                              const float* __restrict__ W,
                                              const float* __restrict__ b,
                                              unsigned short* __restrict__ hb) {
  int gid = blockIdx.x * 256 + threadIdx.x;
  int n = gid >> 6, d = gid & 63;
  const float* xr = x + (size_t)n * FIN;
  float acc = b[d];
#pragma unroll
  for (int k = 0; k < FIN; k++) acc += xr[k] * W[k * DD + d];
  hb[gid] = (unsigned short)f2bf(acc);
}

// ---------------- weight prep: bf16 W^T ----------------
struct WPrep { const float* W[8]; };

__global__ __launch_bounds__(256) void k_wprep(WPrep P, short* __restrict__ wbt) {
  int gid = blockIdx.x * 256 + threadIdx.x;  // 24*4096
  int slot = gid >> 12;
  int e = gid & 4095;
  int n = e >> 6, k = e & 63;
  int bg = slot / NL, l = slot % NL;
  float v = P.W[bg][(size_t)l * 4096 + k * 64 + n];
  wbt[gid] = f2bf(v);
}

// ---------------- segment mean (bf16 out) ----------------
__global__ __launch_bounds__(256) void k_gmean(const unsigned short* __restrict__ hb,
                                               const int* __restrict__ nsorted,
                                               const int* __restrict__ noff,
                                               const int* __restrict__ ncnt,
                                               const float* __restrict__ cinv,
                                               unsigned short* __restrict__ gsumb) {
  __shared__ float red[256];
  int s = blockIdx.x;
  int tid = threadIdx.x;
  int ch = tid & 63, r = tid >> 6;
  int base = noff[s], c = ncnt[s];
  float acc = 0.0f;
  int i = r;
  for (; i + 12 < c; i += 16) {
    int n0 = nsorted[base + i];
    int n1 = nsorted[base + i + 4];
    int n2 = nsorted[base + i + 8];
    int n3 = nsorted[base + i + 12];
    acc += bfu(hb[(size_t)n0 * 64 + ch]) + bfu(hb[(size_t)n1 * 64 + ch]) +
           bfu(hb[(size_t)n2 * 64 + ch]) + bfu(hb[(size_t)n3 * 64 + ch]);
  }
  for (; i < c; i += 4) acc += bfu(hb[(size_t)nsorted[base + i] * 64 + ch]);
  red[tid] = acc;
  __syncthreads();
  if (r == 0) {
    float vsum = red[ch] + red[64 + ch] + red[128 + ch] + red[192 + ch];
    gsumb[s * 64 + ch] = (unsigned short)f2bf(vsum * cinv[s]);
  }
}

// ---------------- fused node kernel: edge-agg + 4x(MLP+LN), wave-autonomous ----------------
struct NodeArgs {
  const unsigned short* hb;
  const unsigned short* gsumb;
  const unsigned short* eas;
  const int* ssrc;
  const int* eoff;
  const int* ecnt;
  const float* We;
  const float* be;
  const int* nidx;
  const int* root;
  const int* tr;
  const float* eps[4];
  const short* wt1[4];
  const short* wt2[4];
  const float* b1[4];
  const float* b2[4];
  const float* ga[4];
  const float* bb[4];
  unsigned short* hbout;
};

// (256,5): budget 512/5~=102 vs demand ~105 (R11: 23MB residual spill).
// Phase E chain shortened: CSR headers (eoff/ecnt) loaded once per wave
// coalesced, broadcast per row via __shfl -> row chain depth 3 -> 2, and
// the scheduler can run ahead into the next row's loads.
__global__ __launch_bounds__(256, 5) void k_node(NodeArgs A) {
  __shared__ short sT[4][16 * LDH];  // per-wave band (DS ops are wave-in-order: no barriers)
  int tid = threadIdx.x;
  int wv = tid >> 6;
  int lane = tid & 63;
  int m = lane & 15, q = lane >> 4;
  int row0 = blockIdx.x * 64 + wv * 16;
  int gm = row0 + m;
  bool valid = gm < NN;
  if (!valid) gm = 0;
  short* band = &sT[wv][0];

  // hoist dependent index chain (3 ints) to overlap Phase E
  int s = A.nidx[gm];
  int rv = A.root[s];
  int rt = A.tr[gm];

  // coalesced CSR header load: lane i holds eoff/ecnt of row row0+(i&15)
  int hr = row0 + (lane & 15);
  int eoffL = 0, ecntL = 0;
  if (hr < NN) {
    eoffL = A.eoff[hr];
    ecntL = A.ecnt[hr];
  }

  // ---- Phase E: edge aggregation for this wave's 16 rows (lane = channel) ----
  {
    int d = lane;
    float w[8];
#pragma unroll
    for (int k = 0; k < 8; k++) w[k] = A.We[k * 64 + d];
    float bed = A.be[d];
    for (int rr = 0; rr < 16; rr++) {
      int base = __shfl(eoffL, rr);
      int deg = __shfl(ecntL, rr);
      float acc = 0.0f;
      int i = 0;
      for (; i + 4 <= deg; i += 4) {
        int s0 = A.ssrc[base + i + 0];
        int s1 = A.ssrc[base + i + 1];
        int s2 = A.ssrc[base + i + 2];
        int s3 = A.ssrc[base + i + 3];
        unsigned short g0 = A.hb[(size_t)s0 * 64 + d];
        unsigned short g1 = A.hb[(size_t)s1 * 64 + d];
        unsigned short g2 = A.hb[(size_t)s2 * 64 + d];
        unsigned short g3 = A.hb[(size_t)s3 * 64 + d];
        uint4 a0 = *(const uint4*)&A.eas[(size_t)(base + i + 0) * 8];
        uint4 a1 = *(const uint4*)&A.eas[(size_t)(base + i + 1) * 8];
        uint4 a2 = *(const uint4*)&A.eas[(size_t)(base + i + 2) * 8];
        uint4 a3 = *(const uint4*)&A.eas[(size_t)(base + i + 3) * 8];
        float e0 = bed + bfl(a0.x) * w[0] + bfh(a0.x) * w[1] + bfl(a0.y) * w[2] + bfh(a0.y) * w[3] +
                   bfl(a0.z) * w[4] + bfh(a0.z) * w[5] + bfl(a0.w) * w[6] + bfh(a0.w) * w[7];
        float e1 = bed + bfl(a1.x) * w[0] + bfh(a1.x) * w[1] + bfl(a1.y) * w[2] + bfh(a1.y) * w[3] +
                   bfl(a1.z) * w[4] + bfh(a1.z) * w[5] + bfl(a1.w) * w[6] + bfh(a1.w) * w[7];
        float e2 = bed + bfl(a2.x) * w[0] + bfh(a2.x) * w[1] + bfl(a2.y) * w[2] + bfh(a2.y) * w[3] +
                   bfl(a2.z) * w[4] + bfh(a2.z) * w[5] + bfl(a2.w) * w[6] + bfh(a2.w) * w[7];
        float e3 = bed + bfl(a3.x) * w[0] + bfh(a3.x) * w[1] + bfl(a3.y) * w[2] + bfh(a3.y) * w[3] +
                   bfl(a3.z) * w[4] + bfh(a3.z) * w[5] + bfl(a3.w) * w[6] + bfh(a3.w) * w[7];
        float m0 = bfu(g0) + e0;
        float m1 = bfu(g1) + e1;
        float m2 = bfu(g2) + e2;
        float m3 = bfu(g3) + e3;
        acc += (m0 > 0.0f ? m0 : 0.0f) + (m1 > 0.0f ? m1 : 0.0f) +
               (m2 > 0.0f ? m2 : 0.0f) + (m3 > 0.0f ? m3 : 0.0f);
      }
      if (i + 2 <= deg) {  // pair step: keeps 2 gathers in flight, shortens serial tail
        int s0 = A.ssrc[base + i + 0];
        int s1 = A.ssrc[base + i + 1];
        unsigned short g0 = A.hb[(size_t)s0 * 64 + d];
        unsigned short g1 = A.hb[(size_t)s1 * 64 + d];
        uint4 a0 = *(const uint4*)&A.eas[(size_t)(base + i + 0) * 8];
        uint4 a1 = *(const uint4*)&A.eas[(size_t)(base + i + 1) * 8];
        float e0 = bed + bfl(a0.x) * w[0] + bfh(a0.x) * w[1] + bfl(a0.y) * w[2] + bfh(a0.y) * w[3] +
                   bfl(a0.z) * w[4] + bfh(a0.z) * w[5] + bfl(a0.w) * w[6] + bfh(a0.w) * w[7];
        float e1 = bed + bfl(a1.x) * w[0] + bfh(a1.x) * w[1] + bfl(a1.y) * w[2] + bfh(a1.y) * w[3] +
                   bfl(a1.z) * w[4] + bfh(a1.z) * w[5] + bfl(a1.w) * w[6] + bfh(a1.w) * w[7];
        float m0 = bfu(g0) + e0;
        float m1 = bfu(g1) + e1;
        acc += (m0 > 0.0f ? m0 : 0.0f) + (m1 > 0.0f ? m1 : 0.0f);
        i += 2;
      }
      if (i < deg) {
        int s0 = A.ssrc[base + i];
        unsigned short g0 = A.hb[(size_t)s0 * 64 + d];
        uint4 a0 = *(const uint4*)&A.eas[(size_t)(base + i) * 8];
        float e0 = bed + bfl(a0.x) * w[0] + bfh(a0.x) * w[1] + bfl(a0.y) * w[2] + bfh(a0.y) * w[3] +
                   bfl(a0.z) * w[4] + bfh(a0.z) * w[5] + bfl(a0.w) * w[6] + bfh(a0.w) * w[7];
        float m0 = bfu(g0) + e0;
        acc += m0 > 0.0f ? m0 : 0.0f;
      }
      band[rr * LDH + d] = f2bf(acc);  // agg row rr, channel d
    }
  }

  // ---- Phase M: 4 branches of MLP+LN (lane = (m,q) fragment role) ----
  float hacc[4][4];
#pragma unroll
  for (int i = 0; i < 4; i++)
#pragma unroll
    for (int j = 0; j < 4; j++) hacc[i][j] = 0.0f;

#pragma unroll 1
  for (int b = 0; b < 4; b++) {
    float aeps = 1.0f + A.eps[b][0];
    // own h-row reloaded each branch (L1/L2-hot; short live range beats 8 held regs)
    const unsigned short* hrow = &A.hb[(size_t)gm * 64];
    uint4 hq0 = *(const uint4*)&hrow[q * 8];
    uint4 hq1 = *(const uint4*)&hrow[32 + q * 8];
    float hv[8], hw[8];
    unp8(hq0, hv);
    unp8(hq1, hw);
    float ov[8], ow[8];
    if (b == 0) {
      // agg from wave-local band (reads complete before GEMM1's T-writes: DS in-order)
      uint4 o0 = *(const uint4*)&band[m * LDH + q * 8];
      uint4 o1 = *(const uint4*)&band[m * LDH + 32 + q * 8];
      unp8(o0, ov);
      unp8(o1, ow);
    } else {
      const unsigned short* r0 = (b == 1) ? &A.hb[(size_t)rv * 64]
                               : (b == 2) ? &A.hb[(size_t)rt * 64]
                                          : &A.gsumb[(size_t)s * 64];
      uint4 o0 = *(const uint4*)&r0[q * 8];
      uint4 o1 = *(const uint4*)&r0[32 + q * 8];
      unp8(o0, ov);
      unp8(o1, ow);
    }

    union { bf16x8 v; uint4 u; } a0u, a1u;
    a0u.u.x = pack2(aeps * hv[0] + ov[0], aeps * hv[1] + ov[1]);
    a0u.u.y = pack2(aeps * hv[2] + ov[2], aeps * hv[3] + ov[3]);
    a0u.u.z = pack2(aeps * hv[4] + ov[4], aeps * hv[5] + ov[5]);
    a0u.u.w = pack2(aeps * hv[6] + ov[6], aeps * hv[7] + ov[7]);
    a1u.u.x = pack2(aeps * hw[0] + ow[0], aeps * hw[1] + ow[1]);
    a1u.u.y = pack2(aeps * hw[2] + ow[2], aeps * hw[3] + ow[3]);
    a1u.u.z = pack2(aeps * hw[4] + ow[4], aeps * hw[5] + ow[5]);
    a1u.u.w = pack2(aeps * hw[6] + ow[6], aeps * hw[7] + ow[7]);

    const short* w1 = A.wt1[b];
    const short* w2 = A.wt2[b];
    const float* b1p = A.b1[b];
    const float* b2p = A.b2[b];

    // GEMM1: T = relu(U @ W1 + b1) -> band (wave-local)
#pragma unroll
    for (int t = 0; t < 4; t++) {
      int n = t * 16 + m;
      bf16x8 w0 = *(const bf16x8*)&w1[n * 64 + q * 8];
      bf16x8 wk = *(const bf16x8*)&w1[n * 64 + 32 + q * 8];
      float bv = b1p[n];
      f32x4 c = {bv, bv, bv, bv};
      c = __builtin_amdgcn_mfma_f32_16x16x32_bf16(a0u.v, w0, c, 0, 0, 0);
      c = __builtin_amdgcn_mfma_f32_16x16x32_bf16(a1u.v, wk, c, 0, 0, 0);
#pragma unroll
      for (int r = 0; r < 4; r++) {
        float v = c[r];
        v = v > 0.0f ? v : 0.0f;
        band[(q * 4 + r) * LDH + n] = f2bf(v);
      }
    }

    bf16x8 t0 = *(const bf16x8*)&band[m * LDH + q * 8];
    bf16x8 t1 = *(const bf16x8*)&band[m * LDH + 32 + q * 8];

    // GEMM2: V = T @ W2 + b2
    f32x4 c2[4];
#pragma unroll
    for (int t = 0; t < 4; t++) {
      int n = t * 16 + m;
      bf16x8 w0 = *(const bf16x8*)&w2[n * 64 + q * 8];
      bf16x8 wk = *(const bf16x8*)&w2[n * 64 + 32 + q * 8];
      float bv = b2p[n];
      f32x4 c = {bv, bv, bv, bv};
      c = __builtin_amdgcn_mfma_f32_16x16x32_bf16(t0, w0, c, 0, 0, 0);
      c = __builtin_amdgcn_mfma_f32_16x16x32_bf16(t1, wk, c, 0, 0, 0);
      c2[t] = c;
    }

    // LayerNorm per row
    const float* ga = A.ga[b];
    const float* bbp = A.bb[b];
    float gav[4], bbv[4];
#pragma unroll
    for (int t = 0; t < 4; t++) {
      gav[t] = ga[t * 16 + m];
      bbv[t] = bbp[t * 16 + m];
    }
#pragma unroll
    for (int r = 0; r < 4; r++) {
      float s1 = c2[0][r] + c2[1][r] + c2[2][r] + c2[3][r];
      float s2 = c2[0][r] * c2[0][r] + c2[1][r] * c2[1][r] +
                 c2[2][r] * c2[2][r] + c2[3][r] * c2[3][r];
#pragma unroll
      for (int o = 1; o < 16; o <<= 1) {
        s1 += __shfl_xor(s1, o);
        s2 += __shfl_xor(s2, o);
      }
      float mu = s1 * (1.0f / 64.0f);
      float var = s2 * (1.0f / 64.0f) - mu * mu;
      float rr = rsqrtf(var + 1e-5f);
#pragma unroll
      for (int t = 0; t < 4; t++)
        hacc[r][t] += (c2[t][r] - mu) * rr * gav[t] + bbv[t];
    }
  }

  // epilogue: LDS roundtrip to coalesce bf16 stores (2x16B per lane)
#pragma unroll
  for (int r = 0; r < 4; r++)
#pragma unroll
    for (int t = 0; t < 4; t++)
      band[(q * 4 + r) * LDH + t * 16 + m] = f2bf(hacc[r][t]);
  if (valid) {
    uint4 v0 = *(const uint4*)&band[m * LDH + q * 8];
    uint4 v1 = *(const uint4*)&band[m * LDH + 32 + q * 8];
    unsigned short* orow = &A.hbout[(size_t)gm * 64];
    *(uint4*)&orow[q * 8] = v0;
    *(uint4*)&orow[32 + q * 8] = v1;
  }
}

// ---------------- fused final pooling + decoder ----------------
__global__ __launch_bounds__(256) void k_pool_out(const unsigned short* __restrict__ hb,
                                                  const int* __restrict__ nsorted,
                                                  const int* __restrict__ noff,
                                                  const int* __restrict__ ncnt,
                                                  const float* __restrict__ W,
                                                  const float* __restrict__ bjk,
                                                  float* __restrict__ out) {
  __shared__ float red[256];
  __shared__ float pr[64];
  int s = blockIdx.x, tid = threadIdx.x;
  int ch = tid & 63, r = tid >> 6;
  int base = noff[s], c = ncnt[s];
  float acc = 0.0f;
  int i = r;
  for (; i + 12 < c; i += 16) {
    int n0 = nsorted[base + i];
    int n1 = nsorted[base + i + 4];
    int n2 = nsorted[base + i + 8];
    int n3 = nsorted[base + i + 12];
    acc += bfu(hb[(size_t)n0 * 64 + ch]) + bfu(hb[(size_t)n1 * 64 + ch]) +
           bfu(hb[(size_t)n2 * 64 + ch]) + bfu(hb[(size_t)n3 * 64 + ch]);
  }
  for (; i < c; i += 4) acc += bfu(hb[(size_t)nsorted[base + i] * 64 + ch]);
  red[tid] = acc;
  __syncthreads();
  if (r == 0) pr[ch] = red[ch] + red[64 + ch] + red[128 + ch] + red[192 + ch];
  __syncthreads();
  if (tid < 64) {
    float o = bjk[tid];
#pragma unroll 8
    for (int k = 0; k < 64; k++) o += pr[k] * W[k * 64 + tid];
    out[s * 64 + tid] = o;
  }
}

extern "C" void kernel_launch(void* const* d_in, const int* in_sizes, int n_in,
                              void* d_out, int out_size, void* d_ws, size_t ws_size,
                              hipStream_t stream) {
  const float* x = (const float*)d_in[0];
  const float* edge_attr = (const float*)d_in[1];
  const int* edge_index = (const int*)d_in[2];
  const int* node_idx = (const int*)d_in[3];
  const int* root_idx = (const int*)d_in[4];
  const int* transpose_idx = (const int*)d_in[5];
  const float* W_init = (const float*)d_in[6];
  const float* b_init = (const float*)d_in[7];
  const float* lu_We = (const float*)d_in[8];
  const float* lu_be = (const float*)d_in[9];
  const float* eps_[4] = {(const float*)d_in[10], (const float*)d_in[17],
                          (const float*)d_in[24], (const float*)d_in[31]};
  const float* W1_[4] = {(const float*)d_in[11], (const float*)d_in[18],
                         (const float*)d_in[25], (const float*)d_in[32]};
  const float* b1_[4] = {(const float*)d_in[12], (const float*)d_in[19],
                         (const float*)d_in[26], (const float*)d_in[33]};
  const float* W2_[4] = {(const float*)d_in[13], (const float*)d_in[20],
                         (const float*)d_in[27], (const float*)d_in[34]};
  const float* b2_[4] = {(const float*)d_in[14], (const float*)d_in[21],
                         (const float*)d_in[28], (const float*)d_in[35]};
  const float* ga_[4] = {(const float*)d_in[15], (const float*)d_in[22],
                         (const float*)d_in[29], (const float*)d_in[36]};
  const float* bn_[4] = {(const float*)d_in[16], (const float*)d_in[23],
                         (const float*)d_in[30], (const float*)d_in[37]};
  const float* W_jk = (const float*)d_in[38];
  const float* b_jk = (const float*)d_in[39];

  // ---- workspace carve (~90 MB) ----
  char* p = (char*)d_ws;
  auto carve = [&](size_t bytes) -> char* {
    char* r = p;
    p += (bytes + 255) & ~(size_t)255;
    return r;
  };
  unsigned short* hb0 = (unsigned short*)carve((size_t)NN * DD * 2);  // 32 MB
  unsigned short* hb1 = (unsigned short*)carve((size_t)NN * DD * 2);  // 32 MB
  unsigned short* gsumb = (unsigned short*)carve(SS * DD * 2);
  float* cinv = (float*)carve(SS * 4);
  short* wbt = (short*)carve(24 * 4096 * 2);
  int* ecnt = (int*)carve(NN * 4);
  int* eoff = (int*)carve(NN * 4);
  int* ecurs = (int*)carve(NN * 4);
  int* ebsum = (int*)carve(256 * 4);
  int* ssrc = (int*)carve((size_t)EE * 4);                             // 4 MB
  unsigned short* eas = (unsigned short*)carve((size_t)EE * FEE * 2);  // 16 MB
  int* ncnt = (int*)carve(SS * 4);
  int* noff = (int*)carve(SS * 4);
  int* ncurs = (int*)carve(SS * 4);
  int* nbsum = (int*)carve(256 * 4);
  int* nsorted = (int*)carve(NN * 4);

  const int* srcp = edge_index;
  const int* dstp = edge_index + EE;

  // ---- build CSRs (identical work every call; graph-capture safe) ----
  hipMemsetAsync(ecnt, 0, NN * 4, stream);
  hipMemsetAsync(ncnt, 0, SS * 4, stream);
  k_hist2<<<EHB + NHB, 256, 0, stream>>>(dstp, node_idx, ecnt, ncnt);
  k_scan1<<<SNB, 256, 0, stream>>>(ecnt, eoff, ecurs, ebsum, NN, nullptr);
  k_scan2<<<1, 256, 0, stream>>>(ebsum, SNB);
  k_scan3<<<SNB, 256, 0, stream>>>(eoff, ecurs, ebsum, NN);
  k_scan1<<<1, 256, 0, stream>>>(ncnt, noff, ncurs, nbsum, SS, cinv);
  k_bucket2<<<EHB + NHB, 256, 0, stream>>>(srcp, dstp, edge_attr, ecurs, ssrc, eas,
                                           node_idx, ncurs, nsorted);

  k_init<<<(NN * DD) / 256, 256, 0, stream>>>(x, W_init, b_init, hb0);

  WPrep P;
  for (int b = 0; b < 4; b++) {
    P.W[b * 2 + 0] = W1_[b];
    P.W[b * 2 + 1] = W2_[b];
  }
  k_wprep<<<(24 * 4096) / 256, 256, 0, stream>>>(P, wbt);

  unsigned short* hbc = hb0;
  unsigned short* hbn = hb1;
  for (int l = 0; l < NL; l++) {
    k_gmean<<<SS, 256, 0, stream>>>(hbc, nsorted, noff, ncnt, cinv, gsumb);

    NodeArgs A;
    A.hb = hbc; A.gsumb = gsumb;
    A.eas = eas; A.ssrc = ssrc; A.eoff = eoff; A.ecnt = ecnt;
    A.We = lu_We + (size_t)l * FEE * DD;
    A.be = lu_be + l * DD;
    A.nidx = node_idx; A.root = root_idx; A.tr = transpose_idx;
    for (int b = 0; b < 4; b++) {
      A.eps[b] = eps_[b] + l;
      A.wt1[b] = wbt + ((size_t)(b * 2 + 0) * NL + l) * 4096;
      A.wt2[b] = wbt + ((size_t)(b * 2 + 1) * NL + l) * 4096;
      A.b1[b] = b1_[b] + l * DD;
      A.b2[b] = b2_[b] + l * DD;
      A.ga[b] = ga_[b] + l * DD;
      A.bb[b] = bn_[b] + l * DD;
    }
    A.hbout = hbn;
    k_node<<<(NN + 63) / 64, 256, 0, stream>>>(A);
    unsigned short* tmpb = hbc; hbc = hbn; hbn = tmpb;
  }

  k_pool_out<<<SS, 256, 0, stream>>>(hbc, nsorted, noff, ncnt, W_jk, b_jk, (float*)d_out);
}